// Round 1
// 402.618 us; speedup vs baseline: 1.0635x; 1.0635x over previous
//
#include <hip/hip_runtime.h>
#include <stdint.h>

typedef unsigned short ushort_t;
typedef __attribute__((ext_vector_type(8))) short bf16x8;   // 8 bf16 = 4 VGPRs
typedef __attribute__((ext_vector_type(4))) float f32x4;

__device__ __forceinline__ ushort_t f2bf(float f) {
  union { float f; uint32_t u; } v; v.f = f;
  uint32_t u = v.u;
  u += 0x7FFFu + ((u >> 16) & 1u);   // RNE
  return (ushort_t)(u >> 16);
}
__device__ __forceinline__ float bf2f(ushort_t h) {
  union { uint32_t u; float f; } v; v.u = ((uint32_t)h) << 16;
  return v.f;
}
__device__ __forceinline__ void gl2lds16(const void* g, void* l) {
  __builtin_amdgcn_global_load_lds(
      (__attribute__((address_space(1))) void*)(uintptr_t)g,
      (__attribute__((address_space(3))) void*)(uint32_t)(uintptr_t)l,
      16, 0, 0);
}

// ==================== 256x256 tile, BK=64, 8-wave, 8-phase GEMM ====================
// C = A * Bt^T.  LDS (128 KiB dynamic): A[2buf][2half][128][64] | B[same].
// Chunk-XOR swizzle (16B chunk ^= row&7) applied on BOTH stage-source and ds_read.
// Schedule: 2 K-tiles / 8 phases; 1 half-tile staged per phase; vmcnt(4) at ph4/ph8
// only (counted, never 0 in main loop); raw s_barrier; setprio(1) around MFMA.
// Ledger (iter i): ph1:B(2i+1,h0) ph2:B(2i+1,h1) ph3:A(2i+2,h0) ph4:A(2i+2,h1)
//                  ph5:B(2i+2,h0) ph6:B(2i+2,h1) ph7:A(2i+3,h0) ph8:A(2i+3,h1)
// Reads of a half COMPLETE before that phase's MFMA (reg deps) and its end-barrier,
// so the stage >=1 phase later never races; every read is covered by a prior
// vmcnt(4)+barrier (verified: vmcnt(4) leaves exactly the 4 loads of the last 2
// phases outstanding, and no read needs data staged in the last 2 phases).
__device__ __forceinline__ void gemm256(
    const ushort_t* __restrict__ A, int lda,
    const ushort_t* __restrict__ Bt, int ldb,
    int m0, int n0, int K, char* __restrict__ smem,
    f32x4 (&acc)[8][4]) {
  const int t = threadIdx.x;
  const int lane = t & 63, wid = t >> 6;
  const int wm = wid >> 2, wn = wid & 3;      // 2 M-waves x 4 N-waves
  const int lr = lane & 15, lq = lane >> 4;
  const int nt = K >> 6;

  // staging: half-tile = 128 rows x 64 k = 16KB; 512 thr x 2 x 16B
  const int row0 = t >> 3, row1 = (512 + t) >> 3;
  const int kg0 = (t & 7) ^ (row0 & 7), kg1 = (t & 7) ^ (row1 & 7);
  const ushort_t* a0 = A + (size_t)(m0 + row0) * lda + kg0 * 8;
  const ushort_t* a1 = A + (size_t)(m0 + row1) * lda + kg1 * 8;
  const ushort_t* b0 = Bt + (size_t)(n0 + row0) * ldb + kg0 * 8;
  const ushort_t* b1 = Bt + (size_t)(n0 + row1) * ldb + kg1 * 8;
  const int d0 = t * 16, d1 = (512 + t) * 16;

  const int o0 = lr * 128 + ((lq ^ (lr & 7)) << 4);
  const int o1 = lr * 128 + (((4 + lq) ^ (lr & 7)) << 4);
  const char* aB = smem + wm * 16384;                 // wave's A half base
  const char* bB = smem + 65536 + wn * 8192;          // wave's B sub-half base

#define STG_A(tt, h, buf) do { if ((tt) < nt) { \
    gl2lds16(a0 + (h) * 128 * lda + (tt) * 64, smem + (buf) * 32768 + (h) * 16384 + d0); \
    gl2lds16(a1 + (h) * 128 * lda + (tt) * 64, smem + (buf) * 32768 + (h) * 16384 + d1); } } while (0)
#define STG_B(tt, h, buf) do { if ((tt) < nt) { \
    gl2lds16(b0 + (h) * 128 * ldb + (tt) * 64, smem + 65536 + (buf) * 32768 + (h) * 16384 + d0); \
    gl2lds16(b1 + (h) * 128 * ldb + (tt) * 64, smem + 65536 + (buf) * 32768 + (h) * 16384 + d1); } } while (0)
#define AF_(buf, mig, s) (*(const bf16x8*)(aB + (buf) * 32768 + (mig) * 2048 + o##s))
#define BF_(buf, nig, s) (*(const bf16x8*)(bB + (buf) * 32768 + (nig) * 2048 + o##s))
#define MFMA16(AR, M0, N0) \
    __builtin_amdgcn_s_setprio(1); \
    _Pragma("unroll") \
    for (int mi = 0; mi < 4; ++mi) \
      _Pragma("unroll") \
      for (int ni = 0; ni < 2; ++ni) { \
        acc[(M0) + mi][(N0) + ni] = __builtin_amdgcn_mfma_f32_16x16x32_bf16(AR[mi][0], bF[ni][0], acc[(M0) + mi][(N0) + ni], 0, 0, 0); \
        acc[(M0) + mi][(N0) + ni] = __builtin_amdgcn_mfma_f32_16x16x32_bf16(AR[mi][1], bF[ni][1], acc[(M0) + mi][(N0) + ni], 0, 0, 0); \
      } \
    __builtin_amdgcn_s_setprio(0);

  bf16x8 aLo[4][2], aHi[4][2], bF[2][2];

  // prologue: tile0 fully (buf0), tile1 A-halves (buf1) -> 12 loads, wait 8 oldest
  STG_A(0, 0, 0); STG_A(0, 1, 0); STG_B(0, 0, 0); STG_B(0, 1, 0);
  STG_A(1, 0, 1); STG_A(1, 1, 1);
  asm volatile("s_waitcnt vmcnt(4)" ::: "memory");
  __builtin_amdgcn_s_barrier();

  const int niter = nt >> 1;
  for (int i = 0; i < niter; ++i) {
    const int t2 = 2 * i + 2, t3 = 2 * i + 3;
    // ---- phase 1: tile 2i (buf0), quad (Mlo,Nlo); 12 ds_reads
    #pragma unroll
    for (int mi = 0; mi < 4; ++mi) { aLo[mi][0] = AF_(0, mi, 0); aLo[mi][1] = AF_(0, mi, 1); }
    #pragma unroll
    for (int ni = 0; ni < 2; ++ni) { bF[ni][0] = BF_(0, ni, 0); bF[ni][1] = BF_(0, ni, 1); }
    STG_B(2 * i + 1, 0, 1);
    __builtin_amdgcn_s_barrier();
    MFMA16(aLo, 0, 0)
    __builtin_amdgcn_s_barrier();
    // ---- phase 2: (Mhi,Nlo); 8 ds_reads
    #pragma unroll
    for (int mi = 0; mi < 4; ++mi) { aHi[mi][0] = AF_(0, 4 + mi, 0); aHi[mi][1] = AF_(0, 4 + mi, 1); }
    STG_B(2 * i + 1, 1, 1);
    __builtin_amdgcn_s_barrier();
    MFMA16(aHi, 4, 0)
    __builtin_amdgcn_s_barrier();
    // ---- phase 3: (Mlo,Nhi); 4 ds_reads
    #pragma unroll
    for (int ni = 0; ni < 2; ++ni) { bF[ni][0] = BF_(0, 2 + ni, 0); bF[ni][1] = BF_(0, 2 + ni, 1); }
    STG_A(t2, 0, 0);
    __builtin_amdgcn_s_barrier();
    MFMA16(aLo, 0, 2)
    __builtin_amdgcn_s_barrier();
    // ---- phase 4: (Mhi,Nhi); 0 ds_reads; counted vmcnt
    STG_A(t2, 1, 0);
    __builtin_amdgcn_s_barrier();
    MFMA16(aHi, 4, 2)
    asm volatile("s_waitcnt vmcnt(4)" ::: "memory");
    __builtin_amdgcn_s_barrier();
    // ---- phase 5: tile 2i+1 (buf1), (Mlo,Nlo)
    #pragma unroll
    for (int mi = 0; mi < 4; ++mi) { aLo[mi][0] = AF_(1, mi, 0); aLo[mi][1] = AF_(1, mi, 1); }
    #pragma unroll
    for (int ni = 0; ni < 2; ++ni) { bF[ni][0] = BF_(1, ni, 0); bF[ni][1] = BF_(1, ni, 1); }
    STG_B(t2, 0, 0);
    __builtin_amdgcn_s_barrier();
    MFMA16(aLo, 0, 0)
    __builtin_amdgcn_s_barrier();
    // ---- phase 6: (Mhi,Nlo)
    #pragma unroll
    for (int mi = 0; mi < 4; ++mi) { aHi[mi][0] = AF_(1, 4 + mi, 0); aHi[mi][1] = AF_(1, 4 + mi, 1); }
    STG_B(t2, 1, 0);
    __builtin_amdgcn_s_barrier();
    MFMA16(aHi, 4, 0)
    __builtin_amdgcn_s_barrier();
    // ---- phase 7: (Mlo,Nhi)
    #pragma unroll
    for (int ni = 0; ni < 2; ++ni) { bF[ni][0] = BF_(1, 2 + ni, 0); bF[ni][1] = BF_(1, 2 + ni, 1); }
    STG_A(t3, 0, 1);
    __builtin_amdgcn_s_barrier();
    MFMA16(aLo, 0, 2)
    __builtin_amdgcn_s_barrier();
    // ---- phase 8: (Mhi,Nhi); counted vmcnt
    STG_A(t3, 1, 1);
    __builtin_amdgcn_s_barrier();
    MFMA16(aHi, 4, 2)
    asm volatile("s_waitcnt vmcnt(4)" ::: "memory");
    __builtin_amdgcn_s_barrier();
  }
#undef STG_A
#undef STG_B
#undef AF_
#undef BF_
#undef MFMA16
}

// ---- fused projection: X[16384][1024] @ Wt[2048][1024]^T, grid 512 x 512thr ----
// n0 < 1024  -> Cq bf16 row-major (GATE: multiplied by gate)
// n0 >= 1024 -> K^T/V^T store via LDS-transposed (reuses the 128KB smem)
template <bool GATE>
__global__ __launch_bounds__(512, 2) void proj8(
    const ushort_t* __restrict__ X, const ushort_t* __restrict__ Wt,
    ushort_t* __restrict__ Cq, ushort_t* __restrict__ Ct,
    const ushort_t* __restrict__ gate) {
  extern __shared__ char smem[];
  const int bid = blockIdx.x;
  const int xcd = bid & 7, i = bid >> 3;        // XCD owns contiguous m-slab
  const int m0 = (xcd * 8 + (i >> 3)) * 256;
  const int n0 = (i & 7) * 256;
  f32x4 acc[8][4] = {};
  gemm256(X, 1024, Wt, 1024, m0, n0, 1024, smem, acc);

  const int t = threadIdx.x, lane = t & 63, wid = t >> 6;
  const int wm = wid >> 2, wn = wid & 3;
  const int lr = lane & 15, lq = lane >> 4;

  if (n0 < 1024) {
    #pragma unroll
    for (int mi = 0; mi < 8; ++mi) {
      int rbase = m0 + wm * 128 + mi * 16 + lq * 4;
      #pragma unroll
      for (int ni = 0; ni < 4; ++ni) {
        int c = n0 + wn * 64 + ni * 16 + lr;
        #pragma unroll
        for (int r = 0; r < 4; ++r) {
          float v = acc[mi][ni][r];
          if constexpr (GATE) v *= bf2f(gate[(size_t)(rbase + r) * 1024 + c]);
          Cq[(size_t)(rbase + r) * 1024 + c] = f2bf(v);
        }
      }
    }
  } else {
    __syncthreads();
    // stage C^T (d-major) in LDS: [256 d][256 ns], 16B-chunk xor swizzle
    #pragma unroll
    for (int mi = 0; mi < 8; ++mi) {
      int ns0 = wm * 128 + mi * 16 + lq * 4;          // local nseq, 4 consecutive
      int nc = ns0 >> 3, half8 = (ns0 >> 2) & 1;
      #pragma unroll
      for (int ni = 0; ni < 4; ++ni) {
        int dl = wn * 64 + ni * 16 + lr;              // local d
        ushort4 u = make_ushort4(f2bf(acc[mi][ni][0]), f2bf(acc[mi][ni][1]),
                                 f2bf(acc[mi][ni][2]), f2bf(acc[mi][ni][3]));
        *(ushort4*)(smem + dl * 512 + ((nc ^ (dl & 31)) * 16) + half8 * 8) = u;
      }
    }
    __syncthreads();
    const int b = m0 >> 12, nseq0 = m0 & 4095;
    #pragma unroll
    for (int j = 0; j < 16; ++j) {
      int g = j * 512 + t;
      int dl = g >> 5, nc = g & 31;
      bf16x8 v = *(const bf16x8*)(smem + dl * 512 + ((nc ^ (dl & 31)) * 16));
      int d = n0 - 1024 + dl;
      *(bf16x8*)&Ct[(((size_t)(b * 1024 + d)) << 12) + nseq0 + nc * 8] = v;
    }
  }
}

// ---- split-K KV, grid 256: XCD owns 2 z-slices; bf16 partials ----
__global__ __launch_bounds__(512, 2) void kv8(
    const ushort_t* __restrict__ VT, const ushort_t* __restrict__ KT,
    ushort_t* __restrict__ P) {
  extern __shared__ char smem[];
  const int bid = blockIdx.x;
  const int xcd = bid & 7, i = bid >> 3;        // i: 0..31
  const int z = xcd * 2 + (i >> 4);
  const int mn = i & 15;
  const int m0 = (mn >> 2) * 256, n0 = (mn & 3) * 256;
  const int b = z & 3, s = z >> 2;
  const ushort_t* A = VT + ((size_t)b << 22) + s * 1024;
  const ushort_t* Bt = KT + ((size_t)b << 22) + s * 1024;
  f32x4 acc[8][4] = {};
  gemm256(A, 4096, Bt, 4096, m0, n0, 1024, smem, acc);

  const int t = threadIdx.x, lane = t & 63, wid = t >> 6;
  const int wm = wid >> 2, wn = wid & 3;
  const int lr = lane & 15, lq = lane >> 4;
  ushort_t* C = P + ((size_t)z << 20);
  #pragma unroll
  for (int mi = 0; mi < 8; ++mi) {
    int rbase = m0 + wm * 128 + mi * 16 + lq * 4;
    #pragma unroll
    for (int ni = 0; ni < 4; ++ni) {
      int c = n0 + wn * 64 + ni * 16 + lr;
      #pragma unroll
      for (int r = 0; r < 4; ++r)
        C[(size_t)(rbase + r) * 1024 + c] = f2bf(acc[mi][ni][r]);
    }
  }
}

__global__ __launch_bounds__(256) void kv_reduce(const ushort_t* __restrict__ P,
                                                 ushort_t* __restrict__ KVT) {
  size_t e4 = ((size_t)blockIdx.x * 256 + threadIdx.x) * 4;  // < 4M
  int b = (int)(e4 >> 20);
  size_t j = e4 & ((1u << 20) - 1);
  float s0 = 0.f, s1 = 0.f, s2 = 0.f, s3 = 0.f;
  #pragma unroll
  for (int sp = 0; sp < 4; ++sp) {
    ushort4 v = *(const ushort4*)(P + ((size_t)(sp * 4 + b) << 20) + j);
    s0 += bf2f(v.x); s1 += bf2f(v.y); s2 += bf2f(v.z); s3 += bf2f(v.w);
  }
  *(ushort4*)&KVT[e4] = make_ushort4(f2bf(s0), f2bf(s1), f2bf(s2), f2bf(s3));
}

// ---- final: Out[m][e] = sum_d Q[m][d] * KVT[b(m)][e][d], fp32 out, grid 256 ----
__global__ __launch_bounds__(512, 2) void fin8(
    const ushort_t* __restrict__ Q, const ushort_t* __restrict__ KVT,
    float* __restrict__ Out) {
  extern __shared__ char smem[];
  const int bid = blockIdx.x;
  const int xcd = bid & 7, i = bid >> 3;        // i: 0..31
  const int m0 = (xcd * 8 + (i >> 2)) * 256;
  const int n0 = (i & 3) * 256;
  const int b = m0 >> 12;
  f32x4 acc[8][4] = {};
  gemm256(Q, 1024, KVT + ((size_t)b << 20), 1024, m0, n0, 1024, smem, acc);

  const int t = threadIdx.x, lane = t & 63, wid = t >> 6;
  const int wm = wid >> 2, wn = wid & 3;
  const int lr = lane & 15, lq = lane >> 4;
  #pragma unroll
  for (int mi = 0; mi < 8; ++mi) {
    int rbase = m0 + wm * 128 + mi * 16 + lq * 4;
    #pragma unroll
    for (int ni = 0; ni < 4; ++ni) {
      int c = n0 + wn * 64 + ni * 16 + lr;
      #pragma unroll
      for (int r = 0; r < 4; ++r)
        Out[(size_t)(rbase + r) * 1024 + c] = acc[mi][ni][r];
    }
  }
}

// ---- prep: 4x weight transpose+convert planes, then X fp32->bf16 ----
__global__ __launch_bounds__(256) void prep(
    const float* __restrict__ xr, const float* __restrict__ xi,
    const float* w0, const float* w1, const float* w2, const float* w3,
    ushort_t* __restrict__ xrb, ushort_t* __restrict__ xib,
    ushort_t* o0, ushort_t* o1, ushort_t* o2, ushort_t* o3) {
  const int bid = blockIdx.x;
  const int t = threadIdx.x;
  if (bid < 4096) {
    __shared__ float tile[32][33];
    const float* W; ushort_t* O;
    switch (bid >> 10) {
      case 0: W = w0; O = o0; break;
      case 1: W = w1; O = o1; break;
      case 2: W = w2; O = o2; break;
      default: W = w3; O = o3; break;
    }
    const int within = bid & 1023;
    const int bx = (within & 31) * 32, by = (within >> 5) * 32;
    const int tx = t & 31, ty = t >> 5;   // (32, 8)
    #pragma unroll
    for (int k = 0; k < 32; k += 8)
      tile[ty + k][tx] = W[(size_t)(by + ty + k) * 1024 + bx + tx];
    __syncthreads();
    #pragma unroll
    for (int k = 0; k < 32; k += 8)
      O[(size_t)(bx + ty + k) * 1024 + by + tx] = f2bf(tile[tx][ty + k]);
  } else {
    const size_t T = 16u * 1024u * 1024u;
    size_t e = ((size_t)(bid - 4096) * 256 + t) * 8;
    const float* src; ushort_t* dst;
    if (e < T) { src = xr + e; dst = xrb + e; }
    else       { src = xi + (e - T); dst = xib + (e - T); }
    float4 f0 = *(const float4*)src;
    float4 f1 = *(const float4*)(src + 4);
    ushort4 u0 = make_ushort4(f2bf(f0.x), f2bf(f0.y), f2bf(f0.z), f2bf(f0.w));
    ushort4 u1 = make_ushort4(f2bf(f1.x), f2bf(f1.y), f2bf(f1.z), f2bf(f1.w));
    *(ushort4*)dst = u0;
    *(ushort4*)(dst + 4) = u1;
  }
}

extern "C" void kernel_launch(void* const* d_in, const int* in_sizes, int n_in,
                              void* d_out, int out_size, void* d_ws, size_t ws_size,
                              hipStream_t stream) {
  const float* xr  = (const float*)d_in[0];
  const float* xi  = (const float*)d_in[1];
  const float* wqr = (const float*)d_in[2];
  const float* wqi = (const float*)d_in[3];
  const float* wk  = (const float*)d_in[4];
  const float* wv  = (const float*)d_in[5];

  char* ws = (char*)d_ws;
  const size_t MB = 1024ull * 1024ull;
  ushort_t* WtQR = (ushort_t*)(ws + 0 * MB);    // [WtQR;WtK] contiguous [2048][1024]
  ushort_t* WtK  = (ushort_t*)(ws + 2 * MB);
  ushort_t* WtQI = (ushort_t*)(ws + 4 * MB);    // [WtQI;WtV] contiguous
  ushort_t* WtV  = (ushort_t*)(ws + 6 * MB);
  ushort_t* Xrb  = (ushort_t*)(ws + 8 * MB);    // 32MB; dead after proj1 -> VT overlays
  ushort_t* Xib  = (ushort_t*)(ws + 40 * MB);   // 32MB; dead after proj2 -> KVT overlays
  ushort_t* KT   = (ushort_t*)(ws + 72 * MB);   // 32MB [4][1024][4096]
  ushort_t* Q    = (ushort_t*)(ws + 104 * MB);  // 32MB
  ushort_t* VT   = (ushort_t*)(ws + 8 * MB);    // overlay on Xrb
  ushort_t* KVT  = (ushort_t*)(ws + 40 * MB);   // overlay on Xib, 8MB
  ushort_t* QR   = (ushort_t*)d_out;            // bf16 scratch phase (32MB)
  ushort_t* KVP  = (ushort_t*)d_out;            // [16][1024][1024] bf16 = 32MB phase

  static bool inited = false;
  if (!inited) {
    inited = true;
    hipFuncSetAttribute((const void*)&proj8<false>, hipFuncAttributeMaxDynamicSharedMemorySize, 131072);
    hipFuncSetAttribute((const void*)&proj8<true>,  hipFuncAttributeMaxDynamicSharedMemorySize, 131072);
    hipFuncSetAttribute((const void*)&kv8,          hipFuncAttributeMaxDynamicSharedMemorySize, 131072);
    hipFuncSetAttribute((const void*)&fin8,         hipFuncAttributeMaxDynamicSharedMemorySize, 131072);
  }

  prep<<<20480, 256, 0, stream>>>(xr, xi, wqr, wqi, wk, wv,
                                  Xrb, Xib, WtQR, WtQI, WtK, WtV);
  proj8<false><<<512, 512, 131072, stream>>>(Xrb, WtQR, QR, KT, nullptr);
  proj8<true><<<512, 512, 131072, stream>>>(Xib, WtQI, Q, VT, QR);
  kv8<<<256, 512, 131072, stream>>>(VT, KT, KVP);
  kv_reduce<<<4096, 256, 0, stream>>>(KVP, KVT);
  fin8<<<256, 512, 131072, stream>>>(Q, KVT, (float*)d_out);
}

// Round 3
// 384.773 us; speedup vs baseline: 1.1128x; 1.0464x over previous
//
#include <hip/hip_runtime.h>
#include <stdint.h>

typedef unsigned short ushort_t;
typedef __attribute__((ext_vector_type(8))) short bf16x8;   // 8 bf16 = 4 VGPRs
typedef __attribute__((ext_vector_type(4))) float f32x4;

__device__ __forceinline__ ushort_t f2bf(float f) {
  union { float f; uint32_t u; } v; v.f = f;
  uint32_t u = v.u;
  u += 0x7FFFu + ((u >> 16) & 1u);   // RNE
  return (ushort_t)(u >> 16);
}
__device__ __forceinline__ float bf2f(ushort_t h) {
  union { uint32_t u; float f; } v; v.u = ((uint32_t)h) << 16;
  return v.f;
}
__device__ __forceinline__ void gl2lds16(const void* g, void* l) {
  __builtin_amdgcn_global_load_lds(
      (__attribute__((address_space(1))) void*)(uintptr_t)g,
      (__attribute__((address_space(3))) void*)(uint32_t)(uintptr_t)l,
      16, 0, 0);
}

// ==================== 256x256 tile, BK=64, 8-wave, 8-phase GEMM ====================
// C = A * Bt^T.  LDS (128 KiB dynamic): A[2buf][2half][128][64] | B[same].
// Chunk-XOR swizzle (16B chunk ^= row&7) on BOTH stage-source and ds_read.
// ONE barrier per phase (lgkmcnt(0)+s_barrier, memory-clobbered asm).
// vmcnt LEDGER (per wave, 2 loads per STG):
//   steady state at ph4/ph8 vmcnt(4): 12 outstanding = [A(t+1)x4 carry,
//   B(t+1)x4, A(t+2)x4]; drain-to-4 retires exactly tile t+1 before its reads.
// TAIL (peeled last iteration): ph3/ph4 A-stages don't exist, so the counted
// wait would leave B(nt-1) in flight when ph5 reads it (the round-2 bug).
// The tail instead does vmcnt(0) at ph4 — no later stages, so a full drain is
// free and guarantees tile nt-1 resident.  Main loop stages are unconditional
// (all indices provably < nt).  nt must be even and >= 4 (nt=16 here).
__device__ __forceinline__ void gemm256(
    const ushort_t* __restrict__ A, int lda,
    const ushort_t* __restrict__ Bt, int ldb,
    int m0, int n0, int K, char* __restrict__ smem,
    f32x4 (&acc)[8][4]) {
  const int t = threadIdx.x;
  const int lane = t & 63, wid = t >> 6;
  const int wm = wid >> 2, wn = wid & 3;      // 2 M-waves x 4 N-waves
  const int lr = lane & 15, lq = lane >> 4;
  const int nt = K >> 6;

  // staging: half-tile = 128 rows x 64 k = 16KB; 512 thr x 2 x 16B
  const int row0 = t >> 3, row1 = (512 + t) >> 3;
  const int kg0 = (t & 7) ^ (row0 & 7), kg1 = (t & 7) ^ (row1 & 7);
  const ushort_t* a0 = A + (size_t)(m0 + row0) * lda + kg0 * 8;
  const ushort_t* a1 = A + (size_t)(m0 + row1) * lda + kg1 * 8;
  const ushort_t* b0 = Bt + (size_t)(n0 + row0) * ldb + kg0 * 8;
  const ushort_t* b1 = Bt + (size_t)(n0 + row1) * ldb + kg1 * 8;
  const int d0 = t * 16, d1 = (512 + t) * 16;

  const int o0 = lr * 128 + ((lq ^ (lr & 7)) << 4);
  const int o1 = lr * 128 + (((4 + lq) ^ (lr & 7)) << 4);
  const char* aB = smem + wm * 16384;                 // wave's A half base
  const char* bB = smem + 65536 + wn * 8192;          // wave's B sub-half base

#define BARX() asm volatile("s_waitcnt lgkmcnt(0)\n\ts_barrier" ::: "memory")
#define VMC4() asm volatile("s_waitcnt vmcnt(4)" ::: "memory")
#define VMC0() asm volatile("s_waitcnt vmcnt(0)" ::: "memory")
#define STG_A(tt, h, buf) do { \
    gl2lds16(a0 + (h) * 128 * lda + (tt) * 64, smem + (buf) * 32768 + (h) * 16384 + d0); \
    gl2lds16(a1 + (h) * 128 * lda + (tt) * 64, smem + (buf) * 32768 + (h) * 16384 + d1); } while (0)
#define STG_B(tt, h, buf) do { \
    gl2lds16(b0 + (h) * 128 * ldb + (tt) * 64, smem + 65536 + (buf) * 32768 + (h) * 16384 + d0); \
    gl2lds16(b1 + (h) * 128 * ldb + (tt) * 64, smem + 65536 + (buf) * 32768 + (h) * 16384 + d1); } while (0)
#define AF_(buf, mig, s) (*(const bf16x8*)(aB + (buf) * 32768 + (mig) * 2048 + o##s))
#define BF_(buf, nig, s) (*(const bf16x8*)(bB + (buf) * 32768 + (nig) * 2048 + o##s))
#define RD_BLO(buf) \
    _Pragma("unroll") \
    for (int ni = 0; ni < 2; ++ni) { bF[ni][0] = BF_(buf, ni, 0); bF[ni][1] = BF_(buf, ni, 1); }
#define RD_BHI(buf) \
    _Pragma("unroll") \
    for (int ni = 0; ni < 2; ++ni) { bF[ni][0] = BF_(buf, 2 + ni, 0); bF[ni][1] = BF_(buf, 2 + ni, 1); }
#define RD_ALO(buf) \
    _Pragma("unroll") \
    for (int mi = 0; mi < 4; ++mi) { aLo[mi][0] = AF_(buf, mi, 0); aLo[mi][1] = AF_(buf, mi, 1); }
#define RD_AHI(buf) \
    _Pragma("unroll") \
    for (int mi = 0; mi < 4; ++mi) { aHi[mi][0] = AF_(buf, 4 + mi, 0); aHi[mi][1] = AF_(buf, 4 + mi, 1); }
#define MFMA16(AR, M0, N0) \
    __builtin_amdgcn_s_setprio(1); \
    _Pragma("unroll") \
    for (int mi = 0; mi < 4; ++mi) \
      _Pragma("unroll") \
      for (int ni = 0; ni < 2; ++ni) { \
        acc[(M0) + mi][(N0) + ni] = __builtin_amdgcn_mfma_f32_16x16x32_bf16(AR[mi][0], bF[ni][0], acc[(M0) + mi][(N0) + ni], 0, 0, 0); \
        acc[(M0) + mi][(N0) + ni] = __builtin_amdgcn_mfma_f32_16x16x32_bf16(AR[mi][1], bF[ni][1], acc[(M0) + mi][(N0) + ni], 0, 0, 0); \
      } \
    __builtin_amdgcn_s_setprio(0);

  bf16x8 aLo[4][2], aHi[4][2], bF[2][2];

  // prologue: tile0 fully (buf0), tile1 A-halves (buf1) -> 12 loads, wait 8 oldest
  STG_A(0, 0, 0); STG_A(0, 1, 0); STG_B(0, 0, 0); STG_B(0, 1, 0);
  STG_A(1, 0, 1); STG_A(1, 1, 1);
  VMC4();
  asm volatile("s_barrier" ::: "memory");

  const int niter = (nt >> 1) - 1;   // main iterations; last pair is peeled
  for (int i = 0; i < niter; ++i) {
    const int t2 = 2 * i + 2, t3 = 2 * i + 3;
    // ---- phase 1: tile 2i (buf0), quad (Mlo,Nlo)
    RD_BLO(0) RD_ALO(0)
    STG_B(2 * i + 1, 0, 1);
    MFMA16(aLo, 0, 0)
    BARX();
    // ---- phase 2: (Mhi,Nlo)
    RD_AHI(0)
    STG_B(2 * i + 1, 1, 1);
    MFMA16(aHi, 4, 0)
    BARX();
    // ---- phase 3: (Mlo,Nhi)
    RD_BHI(0)
    STG_A(t2, 0, 0);
    MFMA16(aLo, 0, 2)
    BARX();
    // ---- phase 4: (Mhi,Nhi); counted vmcnt retires tile 2i+1
    STG_A(t2, 1, 0);
    MFMA16(aHi, 4, 2)
    VMC4();
    BARX();
    // ---- phase 5: tile 2i+1 (buf1), (Mlo,Nlo)
    RD_BLO(1) RD_ALO(1)
    STG_B(t2, 0, 0);
    MFMA16(aLo, 0, 0)
    BARX();
    // ---- phase 6: (Mhi,Nlo)
    RD_AHI(1)
    STG_B(t2, 1, 0);
    MFMA16(aHi, 4, 0)
    BARX();
    // ---- phase 7: (Mlo,Nhi)
    RD_BHI(1)
    STG_A(t3, 0, 1);
    MFMA16(aLo, 0, 2)
    BARX();
    // ---- phase 8: (Mhi,Nhi); counted vmcnt retires tile 2i+2
    STG_A(t3, 1, 1);
    MFMA16(aHi, 4, 2)
    VMC4();
    BARX();
  }
  // ---- peeled tail: tiles nt-2 (buf0) and nt-1 (buf1); only B(nt-1) stages
  {
    RD_BLO(0) RD_ALO(0)
    STG_B(nt - 1, 0, 1);
    MFMA16(aLo, 0, 0)
    BARX();
    RD_AHI(0)
    STG_B(nt - 1, 1, 1);
    MFMA16(aHi, 4, 0)
    BARX();
    RD_BHI(0)
    MFMA16(aLo, 0, 2)
    BARX();
    MFMA16(aHi, 4, 2)
    VMC0();                          // full drain: tile nt-1 resident (no later stages)
    BARX();
    RD_BLO(1) RD_ALO(1)
    MFMA16(aLo, 0, 0)
    BARX();
    RD_AHI(1)
    MFMA16(aHi, 4, 0)
    BARX();
    RD_BHI(1)
    MFMA16(aLo, 0, 2)
    BARX();
    MFMA16(aHi, 4, 2)
    BARX();
  }
#undef BARX
#undef VMC4
#undef VMC0
#undef STG_A
#undef STG_B
#undef AF_
#undef BF_
#undef RD_BLO
#undef RD_BHI
#undef RD_ALO
#undef RD_AHI
#undef MFMA16
}

// ---- fused projection: X[16384][1024] @ Wt[2048][1024]^T, grid 512 x 512thr ----
// n0 < 1024  -> Cq bf16 row-major (GATE: multiplied by gate)
// n0 >= 1024 -> K^T/V^T store via LDS-transposed (reuses the 128KB smem)
template <bool GATE>
__global__ __launch_bounds__(512, 2) void proj8(
    const ushort_t* __restrict__ X, const ushort_t* __restrict__ Wt,
    ushort_t* __restrict__ Cq, ushort_t* __restrict__ Ct,
    const ushort_t* __restrict__ gate) {
  extern __shared__ char smem[];
  const int bid = blockIdx.x;
  const int xcd = bid & 7, i = bid >> 3;        // XCD owns contiguous m-slab
  const int m0 = (xcd * 8 + (i >> 3)) * 256;
  const int n0 = (i & 7) * 256;
  f32x4 acc[8][4] = {};
  gemm256(X, 1024, Wt, 1024, m0, n0, 1024, smem, acc);

  const int t = threadIdx.x, lane = t & 63, wid = t >> 6;
  const int wm = wid >> 2, wn = wid & 3;
  const int lr = lane & 15, lq = lane >> 4;

  if (n0 < 1024) {
    #pragma unroll
    for (int mi = 0; mi < 8; ++mi) {
      int rbase = m0 + wm * 128 + mi * 16 + lq * 4;
      #pragma unroll
      for (int ni = 0; ni < 4; ++ni) {
        int c = n0 + wn * 64 + ni * 16 + lr;
        #pragma unroll
        for (int r = 0; r < 4; ++r) {
          float v = acc[mi][ni][r];
          if constexpr (GATE) v *= bf2f(gate[(size_t)(rbase + r) * 1024 + c]);
          Cq[(size_t)(rbase + r) * 1024 + c] = f2bf(v);
        }
      }
    }
  } else {
    __syncthreads();
    // stage C^T (d-major) in LDS: [256 d][256 ns], 16B-chunk xor swizzle
    #pragma unroll
    for (int mi = 0; mi < 8; ++mi) {
      int ns0 = wm * 128 + mi * 16 + lq * 4;          // local nseq, 4 consecutive
      int nc = ns0 >> 3, half8 = (ns0 >> 2) & 1;
      #pragma unroll
      for (int ni = 0; ni < 4; ++ni) {
        int dl = wn * 64 + ni * 16 + lr;              // local d
        ushort4 u = make_ushort4(f2bf(acc[mi][ni][0]), f2bf(acc[mi][ni][1]),
                                 f2bf(acc[mi][ni][2]), f2bf(acc[mi][ni][3]));
        *(ushort4*)(smem + dl * 512 + ((nc ^ (dl & 31)) * 16) + half8 * 8) = u;
      }
    }
    __syncthreads();
    const int b = m0 >> 12, nseq0 = m0 & 4095;
    #pragma unroll
    for (int j = 0; j < 16; ++j) {
      int g = j * 512 + t;
      int dl = g >> 5, nc = g & 31;
      bf16x8 v = *(const bf16x8*)(smem + dl * 512 + ((nc ^ (dl & 31)) * 16));
      int d = n0 - 1024 + dl;
      *(bf16x8*)&Ct[(((size_t)(b * 1024 + d)) << 12) + nseq0 + nc * 8] = v;
    }
  }
}

// ---- split-K KV, grid 256: XCD owns 2 z-slices; bf16 partials ----
__global__ __launch_bounds__(512, 2) void kv8(
    const ushort_t* __restrict__ VT, const ushort_t* __restrict__ KT,
    ushort_t* __restrict__ P) {
  extern __shared__ char smem[];
  const int bid = blockIdx.x;
  const int xcd = bid & 7, i = bid >> 3;        // i: 0..31
  const int z = xcd * 2 + (i >> 4);
  const int mn = i & 15;
  const int m0 = (mn >> 2) * 256, n0 = (mn & 3) * 256;
  const int b = z & 3, s = z >> 2;
  const ushort_t* A = VT + ((size_t)b << 22) + s * 1024;
  const ushort_t* Bt = KT + ((size_t)b << 22) + s * 1024;
  f32x4 acc[8][4] = {};
  gemm256(A, 4096, Bt, 4096, m0, n0, 1024, smem, acc);

  const int t = threadIdx.x, lane = t & 63, wid = t >> 6;
  const int wm = wid >> 2, wn = wid & 3;
  const int lr = lane & 15, lq = lane >> 4;
  ushort_t* C = P + ((size_t)z << 20);
  #pragma unroll
  for (int mi = 0; mi < 8; ++mi) {
    int rbase = m0 + wm * 128 + mi * 16 + lq * 4;
    #pragma unroll
    for (int ni = 0; ni < 4; ++ni) {
      int c = n0 + wn * 64 + ni * 16 + lr;
      #pragma unroll
      for (int r = 0; r < 4; ++r)
        C[(size_t)(rbase + r) * 1024 + c] = f2bf(acc[mi][ni][r]);
    }
  }
}

__global__ __launch_bounds__(256) void kv_reduce(const ushort_t* __restrict__ P,
                                                 ushort_t* __restrict__ KVT) {
  size_t e4 = ((size_t)blockIdx.x * 256 + threadIdx.x) * 4;  // < 4M
  int b = (int)(e4 >> 20);
  size_t j = e4 & ((1u << 20) - 1);
  float s0 = 0.f, s1 = 0.f, s2 = 0.f, s3 = 0.f;
  #pragma unroll
  for (int sp = 0; sp < 4; ++sp) {
    ushort4 v = *(const ushort4*)(P + ((size_t)(sp * 4 + b) << 20) + j);
    s0 += bf2f(v.x); s1 += bf2f(v.y); s2 += bf2f(v.z); s3 += bf2f(v.w);
  }
  *(ushort4*)&KVT[e4] = make_ushort4(f2bf(s0), f2bf(s1), f2bf(s2), f2bf(s3));
}

// ---- final: Out[m][e] = sum_d Q[m][d] * KVT[b(m)][e][d], fp32 out, grid 256 ----
__global__ __launch_bounds__(512, 2) void fin8(
    const ushort_t* __restrict__ Q, const ushort_t* __restrict__ KVT,
    float* __restrict__ Out) {
  extern __shared__ char smem[];
  const int bid = blockIdx.x;
  const int xcd = bid & 7, i = bid >> 3;        // i: 0..31
  const int m0 = (xcd * 8 + (i >> 2)) * 256;
  const int n0 = (i & 3) * 256;
  const int b = m0 >> 12;
  f32x4 acc[8][4] = {};
  gemm256(Q, 1024, KVT + ((size_t)b << 20), 1024, m0, n0, 1024, smem, acc);

  const int t = threadIdx.x, lane = t & 63, wid = t >> 6;
  const int wm = wid >> 2, wn = wid & 3;
  const int lr = lane & 15, lq = lane >> 4;
  #pragma unroll
  for (int mi = 0; mi < 8; ++mi) {
    int rbase = m0 + wm * 128 + mi * 16 + lq * 4;
    #pragma unroll
    for (int ni = 0; ni < 4; ++ni) {
      int c = n0 + wn * 64 + ni * 16 + lr;
      #pragma unroll
      for (int r = 0; r < 4; ++r)
        Out[(size_t)(rbase + r) * 1024 + c] = acc[mi][ni][r];
    }
  }
}

// ---- prep: 4x weight transpose+convert planes, then X fp32->bf16 ----
__global__ __launch_bounds__(256) void prep(
    const float* __restrict__ xr, const float* __restrict__ xi,
    const float* w0, const float* w1, const float* w2, const float* w3,
    ushort_t* __restrict__ xrb, ushort_t* __restrict__ xib,
    ushort_t* o0, ushort_t* o1, ushort_t* o2, ushort_t* o3) {
  const int bid = blockIdx.x;
  const int t = threadIdx.x;
  if (bid < 4096) {
    __shared__ float tile[32][33];
    const float* W; ushort_t* O;
    switch (bid >> 10) {
      case 0: W = w0; O = o0; break;
      case 1: W = w1; O = o1; break;
      case 2: W = w2; O = o2; break;
      default: W = w3; O = o3; break;
    }
    const int within = bid & 1023;
    const int bx = (within & 31) * 32, by = (within >> 5) * 32;
    const int tx = t & 31, ty = t >> 5;   // (32, 8)
    #pragma unroll
    for (int k = 0; k < 32; k += 8)
      tile[ty + k][tx] = W[(size_t)(by + ty + k) * 1024 + bx + tx];
    __syncthreads();
    #pragma unroll
    for (int k = 0; k < 32; k += 8)
      O[(size_t)(bx + ty + k) * 1024 + by + tx] = f2bf(tile[tx][ty + k]);
  } else {
    const size_t T = 16u * 1024u * 1024u;
    size_t e = ((size_t)(bid - 4096) * 256 + t) * 8;
    const float* src; ushort_t* dst;
    if (e < T) { src = xr + e; dst = xrb + e; }
    else       { src = xi + (e - T); dst = xib + (e - T); }
    float4 f0 = *(const float4*)src;
    float4 f1 = *(const float4*)(src + 4);
    ushort4 u0 = make_ushort4(f2bf(f0.x), f2bf(f0.y), f2bf(f0.z), f2bf(f0.w));
    ushort4 u1 = make_ushort4(f2bf(f1.x), f2bf(f1.y), f2bf(f1.z), f2bf(f1.w));
    *(ushort4*)dst = u0;
    *(ushort4*)(dst + 4) = u1;
  }
}

extern "C" void kernel_launch(void* const* d_in, const int* in_sizes, int n_in,
                              void* d_out, int out_size, void* d_ws, size_t ws_size,
                              hipStream_t stream) {
  const float* xr  = (const float*)d_in[0];
  const float* xi  = (const float*)d_in[1];
  const float* wqr = (const float*)d_in[2];
  const float* wqi = (const float*)d_in[3];
  const float* wk  = (const float*)d_in[4];
  const float* wv  = (const float*)d_in[5];

  char* ws = (char*)d_ws;
  const size_t MB = 1024ull * 1024ull;
  ushort_t* WtQR = (ushort_t*)(ws + 0 * MB);    // [WtQR;WtK] contiguous [2048][1024]
  ushort_t* WtK  = (ushort_t*)(ws + 2 * MB);
  ushort_t* WtQI = (ushort_t*)(ws + 4 * MB);    // [WtQI;WtV] contiguous
  ushort_t* WtV  = (ushort_t*)(ws + 6 * MB);
  ushort_t* Xrb  = (ushort_t*)(ws + 8 * MB);    // 32MB; dead after proj1 -> VT overlays
  ushort_t* Xib  = (ushort_t*)(ws + 40 * MB);   // 32MB; dead after proj2 -> KVT overlays
  ushort_t* KT   = (ushort_t*)(ws + 72 * MB);   // 32MB [4][1024][4096]
  ushort_t* Q    = (ushort_t*)(ws + 104 * MB);  // 32MB
  ushort_t* VT   = (ushort_t*)(ws + 8 * MB);    // overlay on Xrb
  ushort_t* KVT  = (ushort_t*)(ws + 40 * MB);   // overlay on Xib, 8MB
  ushort_t* QR   = (ushort_t*)d_out;            // bf16 scratch phase (32MB)
  ushort_t* KVP  = (ushort_t*)d_out;            // [16][1024][1024] bf16 = 32MB phase

  static bool inited = false;
  if (!inited) {
    inited = true;
    hipFuncSetAttribute((const void*)&proj8<false>, hipFuncAttributeMaxDynamicSharedMemorySize, 131072);
    hipFuncSetAttribute((const void*)&proj8<true>,  hipFuncAttributeMaxDynamicSharedMemorySize, 131072);
    hipFuncSetAttribute((const void*)&kv8,          hipFuncAttributeMaxDynamicSharedMemorySize, 131072);
    hipFuncSetAttribute((const void*)&fin8,         hipFuncAttributeMaxDynamicSharedMemorySize, 131072);
  }

  prep<<<20480, 256, 0, stream>>>(xr, xi, wqr, wqi, wk, wv,
                                  Xrb, Xib, WtQR, WtQI, WtK, WtV);
  proj8<false><<<512, 512, 131072, stream>>>(Xrb, WtQR, QR, KT, nullptr);
  proj8<true><<<512, 512, 131072, stream>>>(Xib, WtQI, Q, VT, QR);
  kv8<<<256, 512, 131072, stream>>>(VT, KT, KVP);
  kv_reduce<<<4096, 256, 0, stream>>>(KVP, KVT);
  fin8<<<256, 512, 131072, stream>>>(Q, KVT, (float*)d_out);
}